// Round 9
// baseline (268.908 us; speedup 1.0000x reference)
//
#include <hip/hip_runtime.h>
#include <cstdint>

static constexpr int S = 1024;
static constexpr int T = 32;
static constexpr float L2E  = 1.4426950408889634f;  // log2(e)
static constexpr float LN2f = 0.6931471805599453f;  // ln(2)

typedef __attribute__((ext_vector_type(8)))  short  short8;
typedef __attribute__((ext_vector_type(16))) float  float16;
typedef __attribute__((ext_vector_type(2)))  float  f32x2;

union Frag { unsigned u[4]; short8 s; };
union D16  { float16 v; f32x2 p[8]; };   // MFMA acc viewed as 8 reg-pairs

__global__ void crf_zero(float* ws) {
  ws[0] = 0.0f; ws[1] = 0.0f; ((unsigned*)ws)[2] = 0u;
}

__device__ __forceinline__ float bcast_lane(float v, int k) {
  return __uint_as_float((unsigned)__builtin_amdgcn_readlane((int)__float_as_uint(v), k));
}

// single-instruction rounded pack: two f32 -> bf16x2 (lo = first arg).
__device__ __forceinline__ unsigned cvtpk(float lo, float hi) {
  unsigned r;
  asm("v_cvt_pk_bf16_f32 %0, %1, %2" : "=v"(r) : "v"(lo), "v"(hi));
  return r;
}

// unpack a bf16x2 word into an f32x2 pair {lo, hi} (2 ops, pk_mul-ready)
__device__ __forceinline__ f32x2 up2(unsigned w) {
  f32x2 r;
  r[0] = __uint_as_float(w << 16);
  r[1] = __uint_as_float(w & 0xFFFF0000u);
  return r;
}

// async global->LDS, 16 B per lane: dest = wave-uniform base + lane*16.
__device__ __forceinline__ void gload16(const float* src, float* dst) {
  __builtin_amdgcn_global_load_lds(
      (const __attribute__((address_space(1))) unsigned int*)(src),
      (__attribute__((address_space(3))) unsigned int*)(dst),
      16, 0, 0);
}

// sigma: fixed row permutation mapping MFMA C-layout row slots onto B-operand
// row slots (swaps 4-blocks 1<->2 within each 16). With A pre-permuted
// (A'[m][k] = X[m][sig(k)]) the product is exact and D's packed pairs ARE the
// next B-operand - no lane data movement.
__device__ __forceinline__ int sig(int k) {
  int g2 = (k >> 2) & 3;
  if (g2 == 1) g2 = 2; else if (g2 == 2) g2 = 1;
  return (k & ~12) | (g2 << 2);
}

// Block = one batch (512 thr = 8 waves). Active range (head, tail] split into
// 8 equal chunks; wave w folds its chunk into a 32x32 matrix via MFMA in the
// linear 2^x domain (M <- diag(g_j) P^T M).
// R9: the fold chain was latency-bound (~350 cy wall/fold vs ~76 cy issue;
// no pipe >40%) with ~100 cy of exposed LDS latency per fold (diag reads
// consumed right after issue). Fix: stage g as PACKED bf16 pairs and
// register-prefetch each fold's 4 uint2 diag words ONE FOLD AHEAD (two
// alternating 8-reg sets) - the ds_read latency hides under the previous
// fold's MFMAs+VALU. Raw em stays in LDS for the numerator (no log2 rt).
__global__ __launch_bounds__(512, 8) void crf_main(
    const float* __restrict__ em, const int* __restrict__ tags,
    const int* __restrict__ mask, const float* __restrict__ startT,
    const float* __restrict__ trans, const float* __restrict__ endT,
    float* __restrict__ ws, float* __restrict__ out, int B)
{
  // 24 KiB pool. Fold phase: per wave 768 u32 = 2 buf x (256 raw f32 +
  // 128 packed bf16x2). Publish/scan phase: 8 mats x 544 u32 (17 KiB).
  // Phases barrier-separated (union).
  __shared__ __align__(16) unsigned s_pool[6144];
  __shared__ float s_trans[1024];                      // 4 KiB
  __shared__ short s_tags[1024];                       // 2 KiB
  __shared__ unsigned long long s_mb[17];
  __shared__ int   s_head, s_tail, s_cnt, s_K[8];
  __shared__ float s_num[8];

  const int tid = threadIdx.x;
  const int l   = tid & 63;
  const int wv  = tid >> 6;
  const int b   = blockIdx.x;
  const int n   = l & 31;        // MFMA column / tag index
  const int h   = l >> 5;        // lane half

  const float* emb   = em   + (size_t)b * S * T;
  const int*   maskb = mask + (size_t)b * S;
  const int*   tagsb = tags + (size_t)b * S;

  // ---- cooperative staging: tags, trans, mask ballots ----
  for (int i = tid; i < 1024; i += 512) {
    s_tags[i]  = (short)tagsb[i];
    s_trans[i] = trans[i];
  }
  {
    unsigned long long b0 = __ballot(maskb[wv * 128 + l] != 0);
    unsigned long long b1 = __ballot(maskb[wv * 128 + 64 + l] != 0);
    if (l == 0) { s_mb[2 * wv] = b0; s_mb[2 * wv + 1] = b1; }
    if (tid == 0) s_mb[16] = 0ull;
  }

  // ---- A' = sigma-permuted P^T as bf16 frags (lane: m=n, k-slot=8h+2p+par) ----
  Frag Alo, Ahi;
  #pragma unroll
  for (int p = 0; p < 4; ++p) {
    int k0 = 8 * h + 2 * p;
    Alo.u[p] = cvtpk(exp2f(trans[sig(k0 + 0)      * T + n] * L2E),
                     exp2f(trans[sig(k0 + 1)      * T + n] * L2E));
    Ahi.u[p] = cvtpk(exp2f(trans[sig(16 + k0 + 0) * T + n] * L2E),
                     exp2f(trans[sig(16 + k0 + 1) * T + n] * L2E));
  }
  __syncthreads();

  if (wv == 0) {
    int first = 0x7fffffff, last = -1, pc = 0;
    if (l < 16) {
      unsigned long long w = s_mb[l];
      if (w) {
        first = 64 * l + (int)__builtin_ctzll(w);
        last  = 64 * l + 63 - (int)__builtin_clzll(w);
        pc    = (int)__builtin_popcountll(w);
      }
    }
    #pragma unroll
    for (int d = 1; d < 64; d <<= 1) {
      first = min(first, __shfl_xor(first, d));
      last  = max(last,  __shfl_xor(last,  d));
      pc   += __shfl_xor(pc, d);
    }
    if (l == 0) { s_head = first; s_tail = last; s_cnt = pc; }
  }
  __syncthreads();
  const int cnt  = s_cnt;
  const int head = (cnt > 0) ? s_head : 0;
  const int tail = (cnt > 0) ? s_tail : 0;

  // ---- equal-split chunk for this wave ----
  const int span = tail - head;
  const int Lc   = (span + 7) >> 3;
  const int c0   = head + 1 + wv * Lc;
  const int c1   = min(c0 + Lc, tail + 1);

  unsigned* wb0 = s_pool + wv * 768;    // buf0: raw[0..255], pk[256..383]
  unsigned* wb1 = wb0 + 384;            // buf1
  unsigned* bcur = wb0;
  unsigned* bnxt = wb1;

  Frag Blo, Bhi;                    // running M in sigma-storage, init = I
  #pragma unroll
  for (int p = 0; p < 4; ++p) {
    int k0 = 8 * h + 2 * p;
    Blo.u[p] = ((sig(k0) == n)          ? 0x3F80u : 0u) |
               ((sig(k0 + 1) == n)      ? 0x3F800000u : 0u);
    Bhi.u[p] = ((sig(16 + k0) == n)     ? 0x3F80u : 0u) |
               ((sig(16 + k0 + 1) == n) ? 0x3F800000u : 0u);
  }
  int   Kacc  = 0;
  float numer = 0.0f;

  // load the 4 packed diag words of step (d+JJ) for this lane's rows
#define LOADPK(S0, S1, S2, S3, JJ) do {                                      \
    const uint2* pk_ = (const uint2*)pkp + (JJ) * 8;                         \
    S0 = pk_[h]; S1 = pk_[h + 2]; S2 = pk_[h + 4]; S3 = pk_[h + 6];          \
  } while (0)

#define FOLDK(C0, C1, C2, C3, RSC) do {                                      \
    D16 D;                                                                   \
    _Pragma("unroll")                                                        \
    for (int q_ = 0; q_ < 16; ++q_) D.v[q_] = 0.0f;                          \
    D.v = __builtin_amdgcn_mfma_f32_32x32x16_bf16(Alo.s, Blo.s, D.v, 0, 0, 0); \
    D.v = __builtin_amdgcn_mfma_f32_32x32x16_bf16(Ahi.s, Bhi.s, D.v, 0, 0, 0); \
    D.p[0] *= up2(C0.x); D.p[1] *= up2(C0.y);                                \
    D.p[2] *= up2(C1.x); D.p[3] *= up2(C1.y);                                \
    D.p[4] *= up2(C2.x); D.p[5] *= up2(C2.y);                                \
    D.p[6] *= up2(C3.x); D.p[7] *= up2(C3.y);                                \
    if (RSC) {                                                               \
      float mx = fmaxf(fmaxf(fmaxf(D.v[0], D.v[1]), fmaxf(D.v[2], D.v[3])),  \
                       fmaxf(fmaxf(D.v[4], D.v[5]), fmaxf(D.v[6], D.v[7]))); \
      mx = fmaxf(mx, fmaxf(fmaxf(fmaxf(D.v[8], D.v[9]),  fmaxf(D.v[10], D.v[11])), \
                           fmaxf(fmaxf(D.v[12], D.v[13]), fmaxf(D.v[14], D.v[15])))); \
      mx = fmaxf(mx, __shfl_xor(mx, 32));   /* column-0 max (valid bound) */ \
      mx = __uint_as_float((unsigned)__builtin_amdgcn_readfirstlane(         \
               (int)__float_as_uint(mx)));                                   \
      int E = (int)((__float_as_uint(mx) >> 23) & 0xffu);                    \
      float sc = __uint_as_float((unsigned)(254 - E) << 23);                 \
      Kacc += E - 127;                                                       \
      _Pragma("unroll")                                                      \
      for (int q_ = 0; q_ < 16; ++q_) D.v[q_] *= sc;                         \
    }                                                                        \
    Blo.u[0] = cvtpk(D.v[0],  D.v[1]);  Blo.u[1] = cvtpk(D.v[2],  D.v[3]);   \
    Blo.u[2] = cvtpk(D.v[4],  D.v[5]);  Blo.u[3] = cvtpk(D.v[6],  D.v[7]);   \
    Bhi.u[0] = cvtpk(D.v[8],  D.v[9]);  Bhi.u[1] = cvtpk(D.v[10], D.v[11]);  \
    Bhi.u[2] = cvtpk(D.v[12], D.v[13]); Bhi.u[3] = cvtpk(D.v[14], D.v[15]);  \
  } while (0)

  // prologue: async-stage first 8-step window (raw em)
  if (c0 < c1) {
    const int base = min(c0, S - 8);
    gload16(emb + (size_t)base * T + 4 * l, (float*)bcur);
  }

  for (int j0 = c0; j0 < c1; j0 += 8) {
    const int ns   = min(8, c1 - j0);
    const int base = min(j0, S - 8);
    const int d    = j0 - base;          // shift of j0 within loaded window

    // wait this wave's async load, then build packed g = bf16(2^em) pairs
    // (raw em kept for the numerator; wave-private buffer, no barrier)
    asm volatile("s_waitcnt vmcnt(0)" ::: "memory");
    {
      float4 r = ((const float4*)bcur)[l];
      ((uint2*)(bcur + 256))[l] =
          make_uint2(cvtpk(exp2f(r.x * L2E), exp2f(r.y * L2E)),
                     cvtpk(exp2f(r.z * L2E), exp2f(r.w * L2E)));
    }

    // issue next window's async load now; folds below hide its latency
    if (j0 + 8 < c1) {
      const int nb = min(j0 + 8, S - 8);
      gload16(emb + (size_t)nb * T + 4 * l, (float*)bnxt);
    }

    const float*    rawp = (const float*)bcur + d * 32;
    const unsigned* pkp  = bcur + 256 + d * 16;

    // 8-bit applied-mask at arbitrary offset j0 (funnel over ballot words)
    const int w = j0 >> 6, o = j0 & 63;
    unsigned long long bits = s_mb[w] >> o;
    if (o) bits |= s_mb[w + 1] << (64 - o);
    unsigned eff = (unsigned)(bits & 0xFFull) & (unsigned)((1u << ns) - 1u);

    // numerator: lanes 0..ns-1 take one step each (raw em, no log roundtrip)
    if (l < ns && ((eff >> l) & 1u)) {
      int j  = j0 + l;
      int tg = (int)s_tags[j], tp = (int)s_tags[j - 1];
      numer += s_trans[tp * T + tg] + rawp[l * 32 + tg];
    }

    if (eff == 0xFFu) {
      // one-fold-ahead register prefetch: each LOADPK issues ~1 fold before
      // its FOLDK consumes -> LDS latency hidden under MFMAs+VALU
      uint2 a0, a1, a2, a3, b0, b1, b2, b3;
      LOADPK(a0, a1, a2, a3, 0);
      LOADPK(b0, b1, b2, b3, 1); FOLDK(a0, a1, a2, a3, false);
      LOADPK(a0, a1, a2, a3, 2); FOLDK(b0, b1, b2, b3, false);
      LOADPK(b0, b1, b2, b3, 3); FOLDK(a0, a1, a2, a3, false);
      LOADPK(a0, a1, a2, a3, 4); FOLDK(b0, b1, b2, b3, false);
      LOADPK(b0, b1, b2, b3, 5); FOLDK(a0, a1, a2, a3, false);
      LOADPK(a0, a1, a2, a3, 6); FOLDK(b0, b1, b2, b3, false);
      LOADPK(b0, b1, b2, b3, 7); FOLDK(a0, a1, a2, a3, false);
      FOLDK(b0, b1, b2, b3, true);
    } else {
      for (int jj = 0; jj < ns; ++jj)
        if ((eff >> jj) & 1u) {
          uint2 a0, a1, a2, a3;
          LOADPK(a0, a1, a2, a3, jj);
          FOLDK(a0, a1, a2, a3, true);
        }
    }

    unsigned* tmp = bcur; bcur = bnxt; bnxt = tmp;
  }
#undef FOLDK
#undef LOADPK

  // ---- all folds done before the mats overlay is written (union hazard) ----
  __syncthreads();

  // ---- publish chunk matrix (packed bf16 row pairs, sigma-unscrambled) ----
  {
    unsigned* mw = s_pool + wv * 544;
    #pragma unroll
    for (int p = 0; p < 4; ++p) {
      mw[(sig(8 * h + 2 * p)      >> 1) * 34 + n] = Blo.u[p];
      mw[(sig(16 + 8 * h + 2 * p) >> 1) * 34 + n] = Bhi.u[p];
    }
  }
  #pragma unroll
  for (int d = 1; d < 64; d <<= 1) numer += __shfl_xor(numer, d);
  if (l == 0) { s_num[wv] = numer; s_K[wv] = Kacc; }
  __syncthreads();

  // ---- phase 2: wave 0 scans the 8 chunk matrices ----
  if (wv == 0) {
    const int t = n;
    const float em0 = emb[head * T + t];
    float sc0 = (startT[t] + em0) * L2E;
    float m0 = sc0;
    #pragma unroll
    for (int d = 1; d < 32; d <<= 1) m0 = fmaxf(m0, __shfl_xor(m0, d));
    float e = exp2f(sc0 - m0);
    float Mtot = m0;

    const unsigned sh = (t & 1) ? 0u : 16u;   // select row-half of packed word
    for (int c = 0; c < 8; ++c) {
      const unsigned* mw = s_pool + c * 544 + (t >> 1) * 34;
      float acc = 0.0f;
      #pragma unroll
      for (int q2 = 0; q2 < 16; ++q2) {
        uint2 w2 = *(const uint2*)(mw + 2 * q2);
        float vlo = __uint_as_float((w2.x << sh) & 0xFFFF0000u);
        float vhi = __uint_as_float((w2.y << sh) & 0xFFFF0000u);
        acc = fmaf(vlo, bcast_lane(e, 2 * q2), acc);
        acc = fmaf(vhi, bcast_lane(e, 2 * q2 + 1), acc);
      }
      e = acc;
      Mtot += (float)s_K[c];
      float mx = e;
      #pragma unroll
      for (int d = 1; d < 32; d <<= 1) mx = fmaxf(mx, __shfl_xor(mx, d));
      int E = (int)((__float_as_uint(mx) >> 23) & 0xffu);
      e *= __uint_as_float((unsigned)(254 - E) << 23);
      Mtot += (float)(E - 127);
    }

    float fv = e * exp2f(endT[t] * L2E);
    #pragma unroll
    for (int d = 1; d < 32; d <<= 1) fv += __shfl_xor(fv, d);
    float denom = (Mtot + log2f(fv)) * LN2f;

    if (l == 0) {
      if (cnt > 0) {
        float ntot = 0.0f;
        for (int wq = 0; wq < 8; ++wq) ntot += s_num[wq];
        int th = (int)s_tags[head], tt = (int)s_tags[tail];
        ntot += startT[th] + bcast_lane(em0, th) + endT[tt];
        atomicAdd(&ws[0], (denom - ntot) / ((float)cnt + 1e-6f));
        atomicAdd(&ws[1], 1.0f);
      }
      __threadfence();
      unsigned done = atomicAdd((unsigned*)ws + 2, 1u);
      if (done == (unsigned)(B - 1)) {
        __threadfence();
        out[0] = ws[0] / (ws[1] + 1e-6f);
      }
    }
  }
}

extern "C" void kernel_launch(void* const* d_in, const int* in_sizes, int n_in,
                              void* d_out, int out_size, void* d_ws, size_t ws_size,
                              hipStream_t stream) {
  const float* em     = (const float*)d_in[0];
  const int*   tags   = (const int*)d_in[1];
  const int*   mask   = (const int*)d_in[2];
  const float* startT = (const float*)d_in[3];
  const float* trans  = (const float*)d_in[4];
  const float* endT   = (const float*)d_in[5];
  float* out = (float*)d_out;
  float* ws  = (float*)d_ws;

  const int B = in_sizes[0] / (S * T);

  crf_zero<<<1, 1, 0, stream>>>(ws);
  crf_main<<<B, 512, 0, stream>>>(em, tags, mask, startT, trans, endT, ws, out, B);
}